// Round 7
// baseline (616.502 us; speedup 1.0000x reference)
//
#include <hip/hip_runtime.h>
#include <hip/hip_bf16.h>

#define F 128

typedef float floatx2 __attribute__((ext_vector_type(2)));

static __device__ __forceinline__ float4 fp8x4_to_f32(unsigned int w) {
    floatx2 lo = __builtin_amdgcn_cvt_pk_f32_fp8((int)w, false);
    floatx2 hi = __builtin_amdgcn_cvt_pk_f32_fp8((int)w, true);
    return make_float4(lo[0], lo[1], hi[0], hi[1]);
}

static __device__ __forceinline__ unsigned int f32x4_to_fp8(float a, float b, float c, float d) {
    int w = 0;
    w = __builtin_amdgcn_cvt_pk_fp8_f32(a, b, w, false);
    w = __builtin_amdgcn_cvt_pk_fp8_f32(c, d, w, true);
    return (unsigned int)w;
}

// ---------------- CSR build ----------------

__global__ void count_edges_k(const int* __restrict__ col, int* __restrict__ cnt, int E) {
    int e0 = (blockIdx.x * 256 + threadIdx.x) * 4;
    if (e0 + 4 <= E) {
        int4 c = *(const int4*)&col[e0];
        atomicAdd(&cnt[c.x], 1);
        atomicAdd(&cnt[c.y], 1);
        atomicAdd(&cnt[c.z], 1);
        atomicAdd(&cnt[c.w], 1);
    } else {
        for (int e = e0; e < E; e++) atomicAdd(&cnt[col[e]], 1);
    }
}

__global__ void scan1_k(const int* __restrict__ cnt, int* __restrict__ offs,
                        float* __restrict__ dinv, int* __restrict__ bsum, int n) {
    __shared__ int s[1024];
    int tid = threadIdx.x;
    int i = blockIdx.x * 1024 + tid;
    int v = (i < n) ? cnt[i] : 0;
    s[tid] = v;
    __syncthreads();
    for (int off = 1; off < 1024; off <<= 1) {
        int t = (tid >= off) ? s[tid - off] : 0;
        __syncthreads();
        s[tid] += t;
        __syncthreads();
    }
    if (i < n) {
        offs[i] = s[tid] - v;
        dinv[i] = rsqrtf((float)(v + 1));
    }
    if (tid == 1023) bsum[blockIdx.x] = s[1023];
}

__global__ void scan2_k(int* bsum, int nb) {
    __shared__ int s[128];
    int tid = threadIdx.x;
    int v = (tid < nb) ? bsum[tid] : 0;
    s[tid] = v;
    __syncthreads();
    for (int off = 1; off < 128; off <<= 1) {
        int t = (tid >= off) ? s[tid - off] : 0;
        __syncthreads();
        s[tid] += t;
        __syncthreads();
    }
    if (tid < nb) bsum[tid] = s[tid] - v;
}

__global__ void scan3_k(int* __restrict__ offs, int* __restrict__ cursor,
                        const int* __restrict__ bsum, int n, int E) {
    int i = blockIdx.x * 1024 + threadIdx.x;
    if (i < n) {
        int o = offs[i] + bsum[blockIdx.x];
        offs[i] = o;
        cursor[i] = o;
    }
    if (i == n) offs[n] = E;
}

__global__ void fill_k(const int* __restrict__ row, const int* __restrict__ col,
                       int* __restrict__ cursor, int* __restrict__ src, int E) {
    int e0 = (blockIdx.x * 256 + threadIdx.x) * 4;
    if (e0 + 4 <= E) {
        int4 r4 = *(const int4*)&row[e0];
        int4 c4 = *(const int4*)&col[e0];
        src[atomicAdd(&cursor[c4.x], 1)] = r4.x;
        src[atomicAdd(&cursor[c4.y], 1)] = r4.y;
        src[atomicAdd(&cursor[c4.z], 1)] = r4.z;
        src[atomicAdd(&cursor[c4.w], 1)] = r4.w;
    } else {
        for (int e = e0; e < E; e++) {
            int v = col[e];
            int pos = atomicAdd(&cursor[v], 1);
            src[pos] = row[e];
        }
    }
}

// ---------------- GEMM: Y8[r][128] = fp8( dinv[r] * (X[r,:] @ W) ), row-major fp8 ----------------

template <int FP8IN>
__global__ __launch_bounds__(256) void gemm_scale_k(const void* __restrict__ Xin,
                                                    const float* __restrict__ W,
                                                    const float* __restrict__ dinv,
                                                    unsigned int* __restrict__ Y8, int n) {
    __shared__ float Ws[F * F];   // 64 KB
    for (int i = threadIdx.x; i < F * F; i += 256) Ws[i] = W[i];
    __syncthreads();

    int lane = threadIdx.x & 31;
    int rg = threadIdx.x >> 5;
    int jc = lane * 4;
    int r0 = blockIdx.x * 64 + rg * 8;

    const float* Xf = (const float*)Xin;
    const unsigned int* Xu = (const unsigned int*)Xin;

    float4 acc[8];
    int rr[8];
#pragma unroll
    for (int i = 0; i < 8; i++) {
        acc[i] = make_float4(0.f, 0.f, 0.f, 0.f);
        int r = r0 + i;
        rr[i] = (r > n - 1) ? (n - 1) : r;
    }

    for (int k = 0; k < F; k += 4) {
        float4 w0 = *(const float4*)&Ws[(k + 0) * F + jc];
        float4 w1 = *(const float4*)&Ws[(k + 1) * F + jc];
        float4 w2 = *(const float4*)&Ws[(k + 2) * F + jc];
        float4 w3 = *(const float4*)&Ws[(k + 3) * F + jc];
#pragma unroll
        for (int i = 0; i < 8; i++) {
            float4 xv;
            if (FP8IN) {
                xv = fp8x4_to_f32(Xu[(size_t)rr[i] * 32 + (k >> 2)]);
            } else {
                xv = *(const float4*)&Xf[(size_t)rr[i] * F + k];
            }
            acc[i].x = fmaf(xv.x, w0.x, acc[i].x); acc[i].y = fmaf(xv.x, w0.y, acc[i].y);
            acc[i].z = fmaf(xv.x, w0.z, acc[i].z); acc[i].w = fmaf(xv.x, w0.w, acc[i].w);
            acc[i].x = fmaf(xv.y, w1.x, acc[i].x); acc[i].y = fmaf(xv.y, w1.y, acc[i].y);
            acc[i].z = fmaf(xv.y, w1.z, acc[i].z); acc[i].w = fmaf(xv.y, w1.w, acc[i].w);
            acc[i].x = fmaf(xv.z, w2.x, acc[i].x); acc[i].y = fmaf(xv.z, w2.y, acc[i].y);
            acc[i].z = fmaf(xv.z, w2.z, acc[i].z); acc[i].w = fmaf(xv.z, w2.w, acc[i].w);
            acc[i].x = fmaf(xv.w, w3.x, acc[i].x); acc[i].y = fmaf(xv.w, w3.y, acc[i].y);
            acc[i].z = fmaf(xv.w, w3.z, acc[i].z); acc[i].w = fmaf(xv.w, w3.w, acc[i].w);
        }
    }

#pragma unroll
    for (int i = 0; i < 8; i++) {
        int r = r0 + i;
        if (r < n) {
            float s = dinv[r];
            unsigned int pk = f32x4_to_fp8(s * acc[i].x, s * acc[i].y,
                                           s * acc[i].z, s * acc[i].w);
            __builtin_nontemporal_store(pk, &Y8[(size_t)r * 32 + lane]);
        }
    }
}

// ---------------- Aggregation: 32-lane group per node, 8-edge batches ----------------
// Per batch: 8 independent clamped src loads (1 wait), then 8 independent 128B row
// gathers into distinct registers (1 wait), masked accumulate. Minimizes serialized
// memory round-trips per node: ~2*ceil(deg/8)+1 vs the previous ~2*deg/4.

template <int WRITE_H>
__global__ __launch_bounds__(256) void agg_k(const unsigned int* __restrict__ Y8,
                                             const float* __restrict__ dinv,
                                             const int* __restrict__ offs,
                                             const int* __restrict__ src,
                                             const float* __restrict__ bias,
                                             unsigned int* __restrict__ H8,
                                             float* __restrict__ gacc,
                                             int n, int ngroups) {
    int l = threadIdx.x & 31;
    int grp0 = (blockIdx.x * 256 + threadIdx.x) >> 5;

    float4 b = ((const float4*)bias)[l];
    float4 pacc = make_float4(0.f, 0.f, 0.f, 0.f);

    for (int g = grp0; g < n; g += ngroups) {
        unsigned int selfw = Y8[(size_t)g * 32 + l];       // issue early
        int s = offs[g], e = offs[g + 1];
        float dv = dinv[g];                                // issue early

        float4 a0 = fp8x4_to_f32(selfw);
        float4 a1 = make_float4(0.f, 0.f, 0.f, 0.f);
        float4 a2 = make_float4(0.f, 0.f, 0.f, 0.f);
        float4 a3 = make_float4(0.f, 0.f, 0.f, 0.f);

        int em1 = e - 1;
        for (int base = s; base < e; base += 8) {
            // masks first (pure ALU), then 8 independent index loads, then 8 gathers
            int i1 = base + 1, i2 = base + 2, i3 = base + 3;
            int i4 = base + 4, i5 = base + 5, i6 = base + 6, i7 = base + 7;
            float m1 = (i1 <= em1) ? 1.f : 0.f;
            float m2 = (i2 <= em1) ? 1.f : 0.f;
            float m3 = (i3 <= em1) ? 1.f : 0.f;
            float m4 = (i4 <= em1) ? 1.f : 0.f;
            float m5 = (i5 <= em1) ? 1.f : 0.f;
            float m6 = (i6 <= em1) ? 1.f : 0.f;
            float m7 = (i7 <= em1) ? 1.f : 0.f;

            int u0 = src[base];
            int u1 = src[(i1 <= em1) ? i1 : em1];
            int u2 = src[(i2 <= em1) ? i2 : em1];
            int u3 = src[(i3 <= em1) ? i3 : em1];
            int u4 = src[(i4 <= em1) ? i4 : em1];
            int u5 = src[(i5 <= em1) ? i5 : em1];
            int u6 = src[(i6 <= em1) ? i6 : em1];
            int u7 = src[(i7 <= em1) ? i7 : em1];

            unsigned int w0 = Y8[(size_t)u0 * 32 + l];
            unsigned int w1 = Y8[(size_t)u1 * 32 + l];
            unsigned int w2 = Y8[(size_t)u2 * 32 + l];
            unsigned int w3 = Y8[(size_t)u3 * 32 + l];
            unsigned int w4 = Y8[(size_t)u4 * 32 + l];
            unsigned int w5 = Y8[(size_t)u5 * 32 + l];
            unsigned int w6 = Y8[(size_t)u6 * 32 + l];
            unsigned int w7 = Y8[(size_t)u7 * 32 + l];

            float4 t;
            t = fp8x4_to_f32(w0);
            a0.x += t.x; a0.y += t.y; a0.z += t.z; a0.w += t.w;
            t = fp8x4_to_f32(w1);
            a1.x = fmaf(m1, t.x, a1.x); a1.y = fmaf(m1, t.y, a1.y);
            a1.z = fmaf(m1, t.z, a1.z); a1.w = fmaf(m1, t.w, a1.w);
            t = fp8x4_to_f32(w2);
            a2.x = fmaf(m2, t.x, a2.x); a2.y = fmaf(m2, t.y, a2.y);
            a2.z = fmaf(m2, t.z, a2.z); a2.w = fmaf(m2, t.w, a2.w);
            t = fp8x4_to_f32(w3);
            a3.x = fmaf(m3, t.x, a3.x); a3.y = fmaf(m3, t.y, a3.y);
            a3.z = fmaf(m3, t.z, a3.z); a3.w = fmaf(m3, t.w, a3.w);
            t = fp8x4_to_f32(w4);
            a0.x = fmaf(m4, t.x, a0.x); a0.y = fmaf(m4, t.y, a0.y);
            a0.z = fmaf(m4, t.z, a0.z); a0.w = fmaf(m4, t.w, a0.w);
            t = fp8x4_to_f32(w5);
            a1.x = fmaf(m5, t.x, a1.x); a1.y = fmaf(m5, t.y, a1.y);
            a1.z = fmaf(m5, t.z, a1.z); a1.w = fmaf(m5, t.w, a1.w);
            t = fp8x4_to_f32(w6);
            a2.x = fmaf(m6, t.x, a2.x); a2.y = fmaf(m6, t.y, a2.y);
            a2.z = fmaf(m6, t.z, a2.z); a2.w = fmaf(m6, t.w, a2.w);
            t = fp8x4_to_f32(w7);
            a3.x = fmaf(m7, t.x, a3.x); a3.y = fmaf(m7, t.y, a3.y);
            a3.z = fmaf(m7, t.z, a3.z); a3.w = fmaf(m7, t.w, a3.w);
        }

        float4 h;
        h.x = fmaxf(fmaf(dv, (a0.x + a1.x) + (a2.x + a3.x), b.x), 0.f);
        h.y = fmaxf(fmaf(dv, (a0.y + a1.y) + (a2.y + a3.y), b.y), 0.f);
        h.z = fmaxf(fmaf(dv, (a0.z + a1.z) + (a2.z + a3.z), b.z), 0.f);
        h.w = fmaxf(fmaf(dv, (a0.w + a1.w) + (a2.w + a3.w), b.w), 0.f);

        if (WRITE_H) {
            __builtin_nontemporal_store(f32x4_to_fp8(h.x, h.y, h.z, h.w),
                                        &H8[(size_t)g * 32 + l]);
        } else {
            pacc.x += h.x; pacc.y += h.y; pacc.z += h.z; pacc.w += h.w;
        }
    }

    if (!WRITE_H) {
        __shared__ float4 red[256];
        red[threadIdx.x] = pacc;
        __syncthreads();
        if (threadIdx.x < 32) {
            float4 a = red[threadIdx.x];
#pragma unroll
            for (int t = 32; t < 256; t += 32) {
                a.x += red[threadIdx.x + t].x;
                a.y += red[threadIdx.x + t].y;
                a.z += red[threadIdx.x + t].z;
                a.w += red[threadIdx.x + t].w;
            }
            atomicAdd(&gacc[threadIdx.x * 4 + 0], a.x);
            atomicAdd(&gacc[threadIdx.x * 4 + 1], a.y);
            atomicAdd(&gacc[threadIdx.x * 4 + 2], a.z);
            atomicAdd(&gacc[threadIdx.x * 4 + 3], a.w);
        }
    }
}

// ---------------- Final: out[a] = sum_k (gacc[k]/N) * Wl[k][a] + bl[a] ----------------

__global__ void final_k(const float* __restrict__ gacc, const float* __restrict__ Wl,
                        const float* __restrict__ bl, float* __restrict__ out, float invN) {
    int a = threadIdx.x;
    if (a < 16) {
        float s = bl[a];
        for (int k = 0; k < 128; k++) s = fmaf(gacc[k] * invN, Wl[k * 16 + a], s);
        out[a] = s;
    }
}

extern "C" void kernel_launch(void* const* d_in, const int* in_sizes, int n_in,
                              void* d_out, int out_size, void* d_ws, size_t ws_size,
                              hipStream_t stream) {
    const float* x  = (const float*)d_in[0];
    const int*   ei = (const int*)d_in[1];
    const float* W1 = (const float*)d_in[2];
    const float* b1 = (const float*)d_in[3];
    const float* W2 = (const float*)d_in[4];
    const float* b2 = (const float*)d_in[5];
    const float* Wl = (const float*)d_in[6];
    const float* bl = (const float*)d_in[7];

    int N = in_sizes[0] / F;
    int E = in_sizes[1] / 2;
    const int* row = ei;
    const int* col = ei + E;

    char* ws = (char*)d_ws;
    size_t off = 0;
    auto alloc = [&](size_t bytes) -> void* {
        void* p = ws + off;
        off = (off + bytes + 255) & ~(size_t)255;
        return p;
    };
    int*          cnt    = (int*)          alloc((size_t)N * 4);
    int*          offs   = (int*)          alloc((size_t)(N + 1) * 4);
    int*          cursor = (int*)          alloc((size_t)N * 4);
    float*        dinv   = (float*)        alloc((size_t)N * 4);
    int*          bsum   = (int*)          alloc(1024 * 4);
    int*          srcb   = (int*)          alloc((size_t)E * 4);
    unsigned int* ybf8   = (unsigned int*) alloc((size_t)N * F);
    unsigned int* hbf8   = (unsigned int*) alloc((size_t)N * F);
    float*        gacc   = (float*)        alloc(128 * 4);

    hipMemsetAsync(cnt, 0, (size_t)N * 4, stream);
    hipMemsetAsync(gacc, 0, 128 * 4, stream);

    int NB = (N + 1023) / 1024;
    count_edges_k<<<(E / 4 + 255) / 256, 256, 0, stream>>>(col, cnt, E);
    scan1_k<<<NB, 1024, 0, stream>>>(cnt, offs, dinv, bsum, N);
    scan2_k<<<1, 128, 0, stream>>>(bsum, NB);
    scan3_k<<<(N + 1024) / 1024, 1024, 0, stream>>>(offs, cursor, bsum, N, E);
    fill_k<<<(E / 4 + 255) / 256, 256, 0, stream>>>(row, col, cursor, srcb, E);

    int GEMM_BLOCKS = (N + 63) / 64;
    const int AGG_BLOCKS = 2048;                  // 8 blocks/CU
    const int NGROUPS = AGG_BLOCKS * 8;           // 32-lane groups

    gemm_scale_k<0><<<GEMM_BLOCKS, 256, 0, stream>>>(x, W1, dinv, ybf8, N);
    agg_k<1><<<AGG_BLOCKS, 256, 0, stream>>>(ybf8, dinv, offs, srcb, b1, hbf8, nullptr, N, NGROUPS);
    gemm_scale_k<1><<<GEMM_BLOCKS, 256, 0, stream>>>(hbf8, W2, dinv, ybf8, N);
    agg_k<0><<<AGG_BLOCKS, 256, 0, stream>>>(ybf8, dinv, offs, srcb, b2, nullptr, gacc, N, NGROUPS);
    final_k<<<1, 64, 0, stream>>>(gacc, Wl, bl, (float*)d_out, 1.0f / (float)N);
}

// Round 8
// 475.020 us; speedup vs baseline: 1.2978x; 1.2978x over previous
//
#include <hip/hip_runtime.h>
#include <hip/hip_bf16.h>

#define F 128

typedef float floatx2 __attribute__((ext_vector_type(2)));

static __device__ __forceinline__ float4 fp8x4_to_f32(unsigned int w) {
    floatx2 lo = __builtin_amdgcn_cvt_pk_f32_fp8((int)w, false);
    floatx2 hi = __builtin_amdgcn_cvt_pk_f32_fp8((int)w, true);
    return make_float4(lo[0], lo[1], hi[0], hi[1]);
}

static __device__ __forceinline__ unsigned int f32x4_to_fp8(float a, float b, float c, float d) {
    int w = 0;
    w = __builtin_amdgcn_cvt_pk_fp8_f32(a, b, w, false);
    w = __builtin_amdgcn_cvt_pk_fp8_f32(c, d, w, true);
    return (unsigned int)w;
}

// decode 16 fp8 (uint4) and masked-accumulate into a[16]
static __device__ __forceinline__ void acc16(float* a, uint4 w, float m) {
    float4 t;
    t = fp8x4_to_f32(w.x);
    a[0]  = fmaf(m, t.x, a[0]);  a[1]  = fmaf(m, t.y, a[1]);
    a[2]  = fmaf(m, t.z, a[2]);  a[3]  = fmaf(m, t.w, a[3]);
    t = fp8x4_to_f32(w.y);
    a[4]  = fmaf(m, t.x, a[4]);  a[5]  = fmaf(m, t.y, a[5]);
    a[6]  = fmaf(m, t.z, a[6]);  a[7]  = fmaf(m, t.w, a[7]);
    t = fp8x4_to_f32(w.z);
    a[8]  = fmaf(m, t.x, a[8]);  a[9]  = fmaf(m, t.y, a[9]);
    a[10] = fmaf(m, t.z, a[10]); a[11] = fmaf(m, t.w, a[11]);
    t = fp8x4_to_f32(w.w);
    a[12] = fmaf(m, t.x, a[12]); a[13] = fmaf(m, t.y, a[13]);
    a[14] = fmaf(m, t.z, a[14]); a[15] = fmaf(m, t.w, a[15]);
}

// ---------------- CSR build ----------------

__global__ void count_edges_k(const int* __restrict__ col, int* __restrict__ cnt, int E) {
    int e0 = (blockIdx.x * 256 + threadIdx.x) * 4;
    if (e0 + 4 <= E) {
        int4 c = *(const int4*)&col[e0];
        atomicAdd(&cnt[c.x], 1);
        atomicAdd(&cnt[c.y], 1);
        atomicAdd(&cnt[c.z], 1);
        atomicAdd(&cnt[c.w], 1);
    } else {
        for (int e = e0; e < E; e++) atomicAdd(&cnt[col[e]], 1);
    }
}

__global__ void scan1_k(const int* __restrict__ cnt, int* __restrict__ offs,
                        float* __restrict__ dinv, int* __restrict__ bsum, int n) {
    __shared__ int s[1024];
    int tid = threadIdx.x;
    int i = blockIdx.x * 1024 + tid;
    int v = (i < n) ? cnt[i] : 0;
    s[tid] = v;
    __syncthreads();
    for (int off = 1; off < 1024; off <<= 1) {
        int t = (tid >= off) ? s[tid - off] : 0;
        __syncthreads();
        s[tid] += t;
        __syncthreads();
    }
    if (i < n) {
        offs[i] = s[tid] - v;
        dinv[i] = rsqrtf((float)(v + 1));
    }
    if (tid == 1023) bsum[blockIdx.x] = s[1023];
}

__global__ void scan2_k(int* bsum, int nb) {
    __shared__ int s[128];
    int tid = threadIdx.x;
    int v = (tid < nb) ? bsum[tid] : 0;
    s[tid] = v;
    __syncthreads();
    for (int off = 1; off < 128; off <<= 1) {
        int t = (tid >= off) ? s[tid - off] : 0;
        __syncthreads();
        s[tid] += t;
        __syncthreads();
    }
    if (tid < nb) bsum[tid] = s[tid] - v;
}

__global__ void scan3_k(int* __restrict__ offs, int* __restrict__ cursor,
                        const int* __restrict__ bsum, int n, int E) {
    int i = blockIdx.x * 1024 + threadIdx.x;
    if (i < n) {
        int o = offs[i] + bsum[blockIdx.x];
        offs[i] = o;
        cursor[i] = o;
    }
    if (i == n) offs[n] = E;
}

__global__ void fill_k(const int* __restrict__ row, const int* __restrict__ col,
                       int* __restrict__ cursor, int* __restrict__ src, int E) {
    int e0 = (blockIdx.x * 256 + threadIdx.x) * 4;
    if (e0 + 4 <= E) {
        int4 r4 = *(const int4*)&row[e0];
        int4 c4 = *(const int4*)&col[e0];
        src[atomicAdd(&cursor[c4.x], 1)] = r4.x;
        src[atomicAdd(&cursor[c4.y], 1)] = r4.y;
        src[atomicAdd(&cursor[c4.z], 1)] = r4.z;
        src[atomicAdd(&cursor[c4.w], 1)] = r4.w;
    } else {
        for (int e = e0; e < E; e++) {
            int v = col[e];
            int pos = atomicAdd(&cursor[v], 1);
            src[pos] = row[e];
        }
    }
}

// ---------------- GEMM: Y8[r][128] = fp8( dinv[r] * (X[r,:] @ W) ), row-major fp8 ----------------

template <int FP8IN>
__global__ __launch_bounds__(256) void gemm_scale_k(const void* __restrict__ Xin,
                                                    const float* __restrict__ W,
                                                    const float* __restrict__ dinv,
                                                    unsigned int* __restrict__ Y8, int n) {
    __shared__ float Ws[F * F];   // 64 KB
    for (int i = threadIdx.x; i < F * F; i += 256) Ws[i] = W[i];
    __syncthreads();

    int lane = threadIdx.x & 31;
    int rg = threadIdx.x >> 5;
    int jc = lane * 4;
    int r0 = blockIdx.x * 64 + rg * 8;

    const float* Xf = (const float*)Xin;
    const unsigned int* Xu = (const unsigned int*)Xin;

    float4 acc[8];
    int rr[8];
#pragma unroll
    for (int i = 0; i < 8; i++) {
        acc[i] = make_float4(0.f, 0.f, 0.f, 0.f);
        int r = r0 + i;
        rr[i] = (r > n - 1) ? (n - 1) : r;
    }

    for (int k = 0; k < F; k += 4) {
        float4 w0 = *(const float4*)&Ws[(k + 0) * F + jc];
        float4 w1 = *(const float4*)&Ws[(k + 1) * F + jc];
        float4 w2 = *(const float4*)&Ws[(k + 2) * F + jc];
        float4 w3 = *(const float4*)&Ws[(k + 3) * F + jc];
#pragma unroll
        for (int i = 0; i < 8; i++) {
            float4 xv;
            if (FP8IN) {
                xv = fp8x4_to_f32(Xu[(size_t)rr[i] * 32 + (k >> 2)]);
            } else {
                xv = *(const float4*)&Xf[(size_t)rr[i] * F + k];
            }
            acc[i].x = fmaf(xv.x, w0.x, acc[i].x); acc[i].y = fmaf(xv.x, w0.y, acc[i].y);
            acc[i].z = fmaf(xv.x, w0.z, acc[i].z); acc[i].w = fmaf(xv.x, w0.w, acc[i].w);
            acc[i].x = fmaf(xv.y, w1.x, acc[i].x); acc[i].y = fmaf(xv.y, w1.y, acc[i].y);
            acc[i].z = fmaf(xv.y, w1.z, acc[i].z); acc[i].w = fmaf(xv.y, w1.w, acc[i].w);
            acc[i].x = fmaf(xv.z, w2.x, acc[i].x); acc[i].y = fmaf(xv.z, w2.y, acc[i].y);
            acc[i].z = fmaf(xv.z, w2.z, acc[i].z); acc[i].w = fmaf(xv.z, w2.w, acc[i].w);
            acc[i].x = fmaf(xv.w, w3.x, acc[i].x); acc[i].y = fmaf(xv.w, w3.y, acc[i].y);
            acc[i].z = fmaf(xv.w, w3.z, acc[i].z); acc[i].w = fmaf(xv.w, w3.w, acc[i].w);
        }
    }

#pragma unroll
    for (int i = 0; i < 8; i++) {
        int r = r0 + i;
        if (r < n) {
            float s = dinv[r];
            unsigned int pk = f32x4_to_fp8(s * acc[i].x, s * acc[i].y,
                                           s * acc[i].z, s * acc[i].w);
            __builtin_nontemporal_store(pk, &Y8[(size_t)r * 32 + lane]);
        }
    }
}

// ---------------- Aggregation: 8-lane group per node (uint4/lane), 32 nodes/block --------
// One wave = 8 concurrent node-chains; a gather instr touches 8 distinct 128B rows = 1KB.
// 4-edge unroll with masked clamp keeps 4 lines in flight per chain.

template <int WRITE_H>
__global__ __launch_bounds__(256) void agg_k(const uint4* __restrict__ Y4,
                                             const float* __restrict__ dinv,
                                             const int* __restrict__ offs,
                                             const int* __restrict__ src,
                                             const float* __restrict__ bias,
                                             uint4* __restrict__ H4,
                                             float* __restrict__ gacc, int n) {
    int l8 = threadIdx.x & 7;          // lane in group: 16 feats
    int grp = threadIdx.x >> 3;        // 0..31: node slot
    int g = blockIdx.x * 32 + grp;

    float a[16];
#pragma unroll
    for (int i = 0; i < 16; i++) a[i] = 0.f;
    float dv = 0.f;

    if (g < n) {
        uint4 selfw = Y4[(size_t)g * 8 + l8];   // issue early
        int s = offs[g], e = offs[g + 1];
        dv = dinv[g];

        acc16(a, selfw, 1.f);

        int em1 = e - 1;
        for (int base = s; base < e; base += 4) {
            int i1 = base + 1, i2 = base + 2, i3 = base + 3;
            float m1 = (i1 <= em1) ? 1.f : 0.f;
            float m2 = (i2 <= em1) ? 1.f : 0.f;
            float m3 = (i3 <= em1) ? 1.f : 0.f;
            int u0 = src[base];
            int u1 = src[(i1 <= em1) ? i1 : em1];
            int u2 = src[(i2 <= em1) ? i2 : em1];
            int u3 = src[(i3 <= em1) ? i3 : em1];
            uint4 w0 = Y4[(size_t)u0 * 8 + l8];
            uint4 w1 = Y4[(size_t)u1 * 8 + l8];
            uint4 w2 = Y4[(size_t)u2 * 8 + l8];
            uint4 w3 = Y4[(size_t)u3 * 8 + l8];
            acc16(a, w0, 1.f);
            acc16(a, w1, m1);
            acc16(a, w2, m2);
            acc16(a, w3, m3);
        }
    }

    // finish: h = relu(dv*a + b); bias loaded late to cut loop register pressure
    float h[16];
    if (g < n) {
        const float4* b4 = (const float4*)bias;
#pragma unroll
        for (int j = 0; j < 4; j++) {
            float4 b = b4[l8 * 4 + j];
            h[j * 4 + 0] = fmaxf(fmaf(dv, a[j * 4 + 0], b.x), 0.f);
            h[j * 4 + 1] = fmaxf(fmaf(dv, a[j * 4 + 1], b.y), 0.f);
            h[j * 4 + 2] = fmaxf(fmaf(dv, a[j * 4 + 2], b.z), 0.f);
            h[j * 4 + 3] = fmaxf(fmaf(dv, a[j * 4 + 3], b.w), 0.f);
        }
    } else {
#pragma unroll
        for (int i = 0; i < 16; i++) h[i] = 0.f;
    }

    if (WRITE_H) {
        if (g < n) {
            uint4 o;
            o.x = f32x4_to_fp8(h[0],  h[1],  h[2],  h[3]);
            o.y = f32x4_to_fp8(h[4],  h[5],  h[6],  h[7]);
            o.z = f32x4_to_fp8(h[8],  h[9],  h[10], h[11]);
            o.w = f32x4_to_fp8(h[12], h[13], h[14], h[15]);
            H4[(size_t)g * 8 + l8] = o;
        }
    } else {
        // reduce over node-slots: wave-local first (lane bits 3..5), then LDS + atomics
#pragma unroll
        for (int i = 0; i < 16; i++) {
            h[i] += __shfl_xor(h[i], 8);
            h[i] += __shfl_xor(h[i], 16);
            h[i] += __shfl_xor(h[i], 32);
        }
        __shared__ float red[4 * 128];
        int w = threadIdx.x >> 6;
        int lane = threadIdx.x & 63;
        if (lane < 8) {
#pragma unroll
            for (int i = 0; i < 16; i++) red[w * 128 + lane * 16 + i] = h[i];
        }
        __syncthreads();
        if (threadIdx.x < 128) {
            float ssum = red[threadIdx.x] + red[128 + threadIdx.x] +
                         red[256 + threadIdx.x] + red[384 + threadIdx.x];
            atomicAdd(&gacc[threadIdx.x], ssum);
        }
    }
}

// ---------------- Final: out[a] = sum_k (gacc[k]/N) * Wl[k][a] + bl[a] ----------------

__global__ void final_k(const float* __restrict__ gacc, const float* __restrict__ Wl,
                        const float* __restrict__ bl, float* __restrict__ out, float invN) {
    int a = threadIdx.x;
    if (a < 16) {
        float s = bl[a];
        for (int k = 0; k < 128; k++) s = fmaf(gacc[k] * invN, Wl[k * 16 + a], s);
        out[a] = s;
    }
}

extern "C" void kernel_launch(void* const* d_in, const int* in_sizes, int n_in,
                              void* d_out, int out_size, void* d_ws, size_t ws_size,
                              hipStream_t stream) {
    const float* x  = (const float*)d_in[0];
    const int*   ei = (const int*)d_in[1];
    const float* W1 = (const float*)d_in[2];
    const float* b1 = (const float*)d_in[3];
    const float* W2 = (const float*)d_in[4];
    const float* b2 = (const float*)d_in[5];
    const float* Wl = (const float*)d_in[6];
    const float* bl = (const float*)d_in[7];

    int N = in_sizes[0] / F;
    int E = in_sizes[1] / 2;
    const int* row = ei;
    const int* col = ei + E;

    char* ws = (char*)d_ws;
    size_t off = 0;
    auto alloc = [&](size_t bytes) -> void* {
        void* p = ws + off;
        off = (off + bytes + 255) & ~(size_t)255;
        return p;
    };
    int*          cnt    = (int*)          alloc((size_t)N * 4);
    int*          offs   = (int*)          alloc((size_t)(N + 1) * 4);
    int*          cursor = (int*)          alloc((size_t)N * 4);
    float*        dinv   = (float*)        alloc((size_t)N * 4);
    int*          bsum   = (int*)          alloc(1024 * 4);
    int*          srcb   = (int*)          alloc((size_t)E * 4);
    unsigned int* ybf8   = (unsigned int*) alloc((size_t)N * F);
    unsigned int* hbf8   = (unsigned int*) alloc((size_t)N * F);
    float*        gacc   = (float*)        alloc(128 * 4);

    hipMemsetAsync(cnt, 0, (size_t)N * 4, stream);
    hipMemsetAsync(gacc, 0, 128 * 4, stream);

    int NB = (N + 1023) / 1024;
    count_edges_k<<<(E / 4 + 255) / 256, 256, 0, stream>>>(col, cnt, E);
    scan1_k<<<NB, 1024, 0, stream>>>(cnt, offs, dinv, bsum, N);
    scan2_k<<<1, 128, 0, stream>>>(bsum, NB);
    scan3_k<<<(N + 1024) / 1024, 1024, 0, stream>>>(offs, cursor, bsum, N, E);
    fill_k<<<(E / 4 + 255) / 256, 256, 0, stream>>>(row, col, cursor, srcb, E);

    int GEMM_BLOCKS = (N + 63) / 64;
    int AGG_BLOCKS = (N + 31) / 32;   // 32 nodes per block, 8-lane groups

    gemm_scale_k<0><<<GEMM_BLOCKS, 256, 0, stream>>>(x, W1, dinv, ybf8, N);
    agg_k<1><<<AGG_BLOCKS, 256, 0, stream>>>((const uint4*)ybf8, dinv, offs, srcb, b1,
                                             (uint4*)hbf8, nullptr, N);
    gemm_scale_k<1><<<GEMM_BLOCKS, 256, 0, stream>>>(hbf8, W2, dinv, ybf8, N);
    agg_k<0><<<AGG_BLOCKS, 256, 0, stream>>>((const uint4*)ybf8, dinv, offs, srcb, b2,
                                             nullptr, gacc, N);
    final_k<<<1, 64, 0, stream>>>(gacc, Wl, bl, (float*)d_out, 1.0f / (float)N);
}